// Round 3
// baseline (752.327 us; speedup 1.0000x reference)
//
#include <hip/hip_runtime.h>
#include <math.h>

#define BB   8
#define SQ   16
#define HIDD 1024
#define NHD  16
#define PAST 4096
#define DH   64
#define SKV  (PAST + SQ)    // 4112
#define NTOK (BB * SQ)      // 128

// ---------------------------------------------------------------------------
// gemm3: C = A(128xK=1024) @ W(1024x1024) + bias, three weight slots selected
// by blockIdx.x>>4. BM=32, BN=64, BK=32, 256 threads, 2x4 micro-tile.
// (round-0 proven version: simple 2-sync staging; cross-block TLP does the
// latency hiding — explicit pipelining regressed twice.)
// ---------------------------------------------------------------------------
__global__ __launch_bounds__(256) void gemm3(
    const float* __restrict__ A,
    const float* __restrict__ W0, const float* __restrict__ W1, const float* __restrict__ W2,
    const float* __restrict__ b0, const float* __restrict__ b1, const float* __restrict__ b2,
    float* __restrict__ O0, float* __restrict__ O1, float* __restrict__ O2)
{
    const int nt   = blockIdx.x;
    const int mt   = blockIdx.y;
    const int wsel = nt >> 4;
    const int col0 = (nt & 15) * 64;
    const int m0   = mt * 32;
    const float* W    = (wsel == 0) ? W0 : (wsel == 1) ? W1 : W2;
    const float* bias = (wsel == 0) ? b0 : (wsel == 1) ? b1 : b2;
    float*       Out  = (wsel == 0) ? O0 : (wsel == 1) ? O1 : O2;

    __shared__ float As[32][33];   // +1 pad
    __shared__ float Bs[32][64];

    const int t    = threadIdx.x;
    const int tm   = t >> 4;          // 0..15 -> rows 2tm,2tm+1
    const int tn   = t & 15;          // cols 4tn..4tn+3
    const int arow = t >> 3;          // 0..31
    const int acol = (t & 7) << 2;    // 0..28
    const int brow = t >> 4;          // 0..15
    const int bcol = (t & 15) << 2;   // 0..60

    float acc0[4] = {0.f,0.f,0.f,0.f};
    float acc1[4] = {0.f,0.f,0.f,0.f};

    for (int k0 = 0; k0 < HIDD; k0 += 32) {
        __syncthreads();
        float4 a4 = *(const float4*)(A + (size_t)(m0 + arow) * HIDD + k0 + acol);
        As[arow][acol+0] = a4.x; As[arow][acol+1] = a4.y;
        As[arow][acol+2] = a4.z; As[arow][acol+3] = a4.w;
        *(float4*)(&Bs[brow][bcol]) =
            *(const float4*)(W + (size_t)(k0 + brow) * HIDD + col0 + bcol);
        *(float4*)(&Bs[brow + 16][bcol]) =
            *(const float4*)(W + (size_t)(k0 + brow + 16) * HIDD + col0 + bcol);
        __syncthreads();
        #pragma unroll
        for (int kk = 0; kk < 32; ++kk) {
            const float  a0 = As[2*tm][kk];
            const float  a1 = As[2*tm + 1][kk];
            const float4 b4 = *(const float4*)(&Bs[kk][tn << 2]);
            acc0[0] += a0*b4.x; acc0[1] += a0*b4.y; acc0[2] += a0*b4.z; acc0[3] += a0*b4.w;
            acc1[0] += a1*b4.x; acc1[1] += a1*b4.y; acc1[2] += a1*b4.z; acc1[3] += a1*b4.w;
        }
    }
    const float4 bb = *(const float4*)(bias + col0 + (tn << 2));
    float* o0 = Out + (size_t)(m0 + 2*tm) * HIDD + col0 + (tn << 2);
    float* o1 = o0 + HIDD;
    o0[0] = acc0[0] + bb.x; o0[1] = acc0[1] + bb.y; o0[2] = acc0[2] + bb.z; o0[3] = acc0[3] + bb.w;
    o1[0] = acc1[0] + bb.x; o1[1] = acc1[1] + bb.y; o1[2] = acc1[2] + bb.z; o1[3] = acc1[3] + bb.w;
}

// ---------------------------------------------------------------------------
// rope_scatter: RoPE over full 1024-dim rows (half = 512, per reference), then
// scatter to head layouts. Q -> ws (B,NH,SQ,DH); K,V -> tails of new_key/new_value.
// ---------------------------------------------------------------------------
__global__ __launch_bounds__(256) void rope_scatter(
    const float* __restrict__ qr, const float* __restrict__ kr, const float* __restrict__ vr,
    const int* __restrict__ pos_ids,
    float* __restrict__ Qh, float* __restrict__ nk, float* __restrict__ nv)
{
    const int tok = blockIdx.x;         // 0..127
    const int b   = tok >> 4;
    const int s   = tok & 15;
    const float pos = (float)pos_ids[tok];
    const size_t rq = (size_t)tok * HIDD;
    for (int i = threadIdx.x; i < 512; i += 256) {
        const float inv = __expf((float)i * (-9.210340371976184f / 512.0f)); // 1/10000^(i/512)
        const float ang = pos * inv;
        float c, sn;
        __sincosf(ang, &sn, &c);
        const int h1 = i >> 6, d = i & 63;
        const int h2 = h1 + 8;           // (i+512)>>6
        float x1, x2;
        x1 = qr[rq + i]; x2 = qr[rq + i + 512];
        Qh[((size_t)(b*NHD + h1)*SQ + s)*DH + d] = x1*c - x2*sn;
        Qh[((size_t)(b*NHD + h2)*SQ + s)*DH + d] = x2*c + x1*sn;
        x1 = kr[rq + i]; x2 = kr[rq + i + 512];
        nk[((size_t)(b*NHD + h1)*SKV + PAST + s)*DH + d] = x1*c - x2*sn;
        nk[((size_t)(b*NHD + h2)*SKV + PAST + s)*DH + d] = x2*c + x1*sn;
        x1 = vr[rq + i]; x2 = vr[rq + i + 512];
        nv[((size_t)(b*NHD + h1)*SKV + PAST + s)*DH + d] = x1;
        nv[((size_t)(b*NHD + h2)*SKV + PAST + s)*DH + d] = x2;
    }
}

// ---------------------------------------------------------------------------
// attn_partial: fused past->new KV copy + flash-style partial attention.
// grid = (nchunks, 128 (b,h)). 256 threads = 4 waves. Round-0 2-sync
// structure (proven fastest). Occupancy lever vs round-0:
//  * V is NOT staged in LDS — PV reads V rows from global; the fused copy
//    touched the 16 KB tile moments earlier so reads hit per-XCD L2.
//  * LDS = Q 4K + K 16K + P 4K = 24 KB -> 6 blocks/CU (was 40 KB -> 4).
//  * nchunks=16 (2048 blocks) so >=6 blocks/CU are actually available.
//  * __launch_bounds__(256,6) caps VGPR at 85 for 6 waves/SIMD.
// Wave w owns queries 4w..4w+3. Scores: lane<->key (XOR-swizzled K tile).
// PV: lane = (q in wave, d/4), P read as float4 from transposed [q][key] LDS.
// ---------------------------------------------------------------------------
__global__ __launch_bounds__(256, 6) void attn_partial(
    const float* __restrict__ pk, const float* __restrict__ pv,
    const float* __restrict__ Qh, const float* __restrict__ amask,
    float* __restrict__ nk, float* __restrict__ nv,
    float* __restrict__ pc, float* __restrict__ pm, float* __restrict__ pl,
    const int nchunks)
{
    const int chunk = blockIdx.x;        // 0..nchunks-1
    const int bh    = blockIdx.y;        // 0..127
    const int b     = bh >> 4;
    const int t     = threadIdx.x;
    const int w     = t >> 6;            // wave 0..3
    const int lane  = t & 63;
    const int qq    = lane >> 4;         // query within wave (PV layout)
    const int d4    = lane & 15;         // float4 index of d (PV layout)

    const int kpc    = PAST / nchunks;   // keys per chunk (256 or 512)
    const int ktiles = kpc >> 6;         // 64-key tiles per chunk

    __shared__ float  Qs[SQ * DH];       // pre-scaled Q (16x64)
    __shared__ float4 Ks[64 * 16];       // swizzled K tile
    __shared__ float  Ps2[4][4][64];     // per-wave P, transposed: [w][q][key]

    // staging indices: pass p covers row j0+16p, float4 i0
    const int j0 = t >> 4;               // 0..15
    const int i0 = t & 15;               // 0..15
    const size_t pbase = (size_t)bh * PAST * DH;
    const size_t nbase = (size_t)bh * SKV  * DH;

    // stage Q, folding in the 1/sqrt(dh) scale
    {
        float4 q4 = *(const float4*)(Qh + ((size_t)bh * SQ + j0) * DH + 4*i0);
        q4.x *= 0.125f; q4.y *= 0.125f; q4.z *= 0.125f; q4.w *= 0.125f;
        *(float4*)(&Qs[j0 * DH + 4*i0]) = q4;
    }

    float m_r[4], l_r[4];
    #pragma unroll
    for (int q = 0; q < 4; ++q) { m_r[q] = -3.0e38f; l_r[q] = 0.0f; }
    float4 ctx = make_float4(0.f, 0.f, 0.f, 0.f);

    const int ntiles = (chunk == nchunks - 1) ? (ktiles + 1) : ktiles;
    for (int tile = 0; tile < ntiles; ++tile) {
        __syncthreads();   // protect LDS reuse from previous iteration
        if (tile < ktiles) {
            const int k0 = chunk * kpc + tile * 64;
            // stage K (swizzled) + fused K/V copy; V goes to global only.
            #pragma unroll
            for (int p = 0; p < 4; ++p) {
                const int j = j0 + 16*p;
                const size_t po = pbase + (size_t)(k0 + j) * DH + 4*i0;
                const size_t no = nbase + (size_t)(k0 + j) * DH + 4*i0;
                const float4 k4 = *(const float4*)(pk + po);
                *(float4*)(nk + no) = k4;                 // fused copy
                Ks[j * 16 + (i0 ^ (j & 7))] = k4;         // swizzled stage
                const float4 v4 = *(const float4*)(pv + po);
                *(float4*)(nv + no) = v4;                 // fused copy (PV reads L2)
            }
        } else {
            // 16 new keys, already rope'd + written to tails by rope_scatter
            Ks[j0 * 16 + (i0 ^ (j0 & 7))] =
                *(const float4*)(nk + nbase + (size_t)(PAST + j0) * DH + 4*i0);
        }
        __syncthreads();

        const int jcount = (tile < ktiles) ? 64 : 16;

        // ---- scores: lane = key, 4 queries per wave ----
        float s[4];
        {
            float4 acc[4];
            #pragma unroll
            for (int q = 0; q < 4; ++q) acc[q] = make_float4(0.f,0.f,0.f,0.f);
            if (lane < jcount) {
                #pragma unroll
                for (int i = 0; i < 16; ++i) {
                    const float4 k4 = Ks[lane * 16 + (i ^ (lane & 7))];
                    #pragma unroll
                    for (int q = 0; q < 4; ++q) {
                        const float4 q4 = *(const float4*)(&Qs[(4*w + q) * DH + 4*i]);
                        acc[q].x += k4.x * q4.x; acc[q].y += k4.y * q4.y;
                        acc[q].z += k4.z * q4.z; acc[q].w += k4.w * q4.w;
                    }
                }
            }
            #pragma unroll
            for (int q = 0; q < 4; ++q)
                s[q] = (lane < jcount) ? (acc[q].x + acc[q].y + acc[q].z + acc[q].w)
                                       : -3.0e38f;
        }
        if (tile == ktiles && lane < 16) {
            #pragma unroll
            for (int q = 0; q < 4; ++q)
                s[q] += amask[((size_t)b * SQ + 4*w + q) * SQ + lane];
        }

        // ---- online softmax per wave ----
        float alpha[4], pjv[4];
        #pragma unroll
        for (int q = 0; q < 4; ++q) {
            float mx = s[q];
            #pragma unroll
            for (int off = 1; off < 64; off <<= 1)
                mx = fmaxf(mx, __shfl_xor(mx, off, 64));
            const float mnew = fmaxf(m_r[q], mx);
            alpha[q] = __expf(m_r[q] - mnew);
            const float p = __expf(s[q] - mnew);
            pjv[q] = p;
            float ps = p;
            #pragma unroll
            for (int off = 1; off < 64; off <<= 1)
                ps += __shfl_xor(ps, off, 64);
            l_r[q] = l_r[q] * alpha[q] + ps;
            m_r[q] = mnew;
        }
        // transposed P write: lane-linear per q, conflict-free; same-wave
        // private region so no extra barrier needed before the read below.
        #pragma unroll
        for (int q = 0; q < 4; ++q)
            Ps2[w][q][lane] = pjv[q];

        // rescale ctx by alpha of this lane's query
        const float asel = (qq == 0) ? alpha[0] : (qq == 1) ? alpha[1]
                         : (qq == 2) ? alpha[2] : alpha[3];
        ctx.x *= asel; ctx.y *= asel; ctx.z *= asel; ctx.w *= asel;

        // ---- PV: lane = (qq, d4); P from LDS float4, V rows from global
        //      (L2-hot: the fused copy just streamed this 16 KB tile). ----
        const float* Pq = &Ps2[w][0][0] + qq * 64;
        const float* Vg = (tile < ktiles)
                        ? (pv + pbase + (size_t)(chunk * kpc + tile * 64) * DH)
                        : (nv + nbase + (size_t)PAST * DH);
        const int j4 = jcount >> 2;
        #pragma unroll 4
        for (int jj = 0; jj < j4; ++jj) {
            const float4 p4 = *(const float4*)(Pq + 4*jj);
            const float4 v0 = *(const float4*)(Vg + (size_t)(4*jj + 0) * DH + 4*d4);
            const float4 v1 = *(const float4*)(Vg + (size_t)(4*jj + 1) * DH + 4*d4);
            const float4 v2 = *(const float4*)(Vg + (size_t)(4*jj + 2) * DH + 4*d4);
            const float4 v3 = *(const float4*)(Vg + (size_t)(4*jj + 3) * DH + 4*d4);
            ctx.x += p4.x*v0.x; ctx.y += p4.x*v0.y; ctx.z += p4.x*v0.z; ctx.w += p4.x*v0.w;
            ctx.x += p4.y*v1.x; ctx.y += p4.y*v1.y; ctx.z += p4.y*v1.z; ctx.w += p4.y*v1.w;
            ctx.x += p4.z*v2.x; ctx.y += p4.z*v2.y; ctx.z += p4.z*v2.z; ctx.w += p4.z*v2.w;
            ctx.x += p4.w*v3.x; ctx.y += p4.w*v3.y; ctx.z += p4.w*v3.z; ctx.w += p4.w*v3.w;
        }
    }

    // write partials (unnormalized ctx + m,l)
    const int blk = bh * nchunks + chunk;
    const int qg  = 4*w + qq;
    *(float4*)(pc + (size_t)blk * 1024 + qg * DH + 4*d4) = ctx;
    if (d4 == 0) {
        const float msel = (qq == 0) ? m_r[0] : (qq == 1) ? m_r[1] : (qq == 2) ? m_r[2] : m_r[3];
        const float lsel = (qq == 0) ? l_r[0] : (qq == 1) ? l_r[1] : (qq == 2) ? l_r[2] : l_r[3];
        pm[blk * 16 + qg] = msel;
        pl[blk * 16 + qg] = lsel;
    }
}

// ---------------------------------------------------------------------------
// attn_reduce: merge nchunks chunk-partials per (b,h), normalize, write ctx
// in (token, hid) layout for the output projection. Per-chunk exp weights
// computed once into LDS.
// ---------------------------------------------------------------------------
__global__ __launch_bounds__(256) void attn_reduce(
    const float* __restrict__ pc, const float* __restrict__ pm,
    const float* __restrict__ pl, float* __restrict__ ctxw,
    const int nchunks)
{
    const int bh = blockIdx.x;
    const int b  = bh >> 4, h = bh & 15;
    const int t  = threadIdx.x;
    __shared__ float wgt[16][SQ];
    __shared__ float li[SQ];
    if (t < SQ) {
        float m = -3.0e38f;
        for (int c = 0; c < nchunks; ++c)
            m = fmaxf(m, pm[(bh*nchunks + c) * 16 + t]);
        float L = 0.f;
        for (int c = 0; c < nchunks; ++c) {
            const float e = __expf(pm[(bh*nchunks + c) * 16 + t] - m);
            L += pl[(bh*nchunks + c) * 16 + t] * e;
            wgt[c][t] = e;
        }
        li[t] = 1.0f / L;
    }
    __syncthreads();
    #pragma unroll
    for (int r = 0; r < 4; ++r) {
        const int idx = t + 256 * r;          // (q,d) in 0..1023
        const int q = idx >> 6, d = idx & 63;
        float acc = 0.f;
        for (int c = 0; c < nchunks; ++c)
            acc += pc[(size_t)(bh*nchunks + c) * 1024 + idx] * wgt[c][q];
        ctxw[((size_t)(b*SQ + q) * NHD + h) * DH + d] = acc * li[q];
    }
}

// ---------------------------------------------------------------------------
extern "C" void kernel_launch(void* const* d_in, const int* in_sizes, int n_in,
                              void* d_out, int out_size, void* d_ws, size_t ws_size,
                              hipStream_t stream)
{
    const float* hidden = (const float*)d_in[0];
    const float* amask  = (const float*)d_in[1];
    const float* past_k = (const float*)d_in[2];
    const float* past_v = (const float*)d_in[3];
    const int*   pos    = (const int*)  d_in[4];
    const float* Wq = (const float*)d_in[5];  const float* bq = (const float*)d_in[6];
    const float* Wk = (const float*)d_in[7];  const float* bk = (const float*)d_in[8];
    const float* Wv = (const float*)d_in[9];  const float* bv = (const float*)d_in[10];
    const float* Wo = (const float*)d_in[11]; const float* bo = (const float*)d_in[12];

    float* out = (float*)d_out;                       // (128,1024)
    float* nk  = out + (size_t)NTOK * HIDD;           // (8,16,4112,64)
    float* nv  = nk + (size_t)BB * NHD * SKV * DH;    // (8,16,4112,64)

    // choose chunk count by workspace capacity (16 needs ~10.8 MB, 8 ~6.6 MB)
    auto ws_need = [](int nc) -> size_t {
        return (size_t)(4 * 131072                 // q_raw,k_raw,v_raw,Qh
                        + nc * 128 * 1024          // pc
                        + 2 * nc * 128 * 16        // pm, pl
                        + 131072)                  // ctxw
               * sizeof(float);
    };
    const int nchunks = (ws_size >= ws_need(16)) ? 16 : 8;

    float* ws     = (float*)d_ws;
    float* q_raw  = ws;                        // 131072
    float* k_raw  = q_raw + 131072;            // 131072
    float* v_raw  = k_raw + 131072;            // 131072
    float* Qh     = v_raw + 131072;            // 131072 (B,NH,SQ,DH)
    float* pc     = Qh    + 131072;            // nchunks*128*1024
    float* pm     = pc    + (size_t)nchunks * 128 * 1024;
    float* pl     = pm    + (size_t)nchunks * 128 * 16;
    float* ctxw   = pl    + (size_t)nchunks * 128 * 16;

    // 1) QKV projections
    gemm3<<<dim3(48, 4), 256, 0, stream>>>(hidden, Wq, Wk, Wv, bq, bk, bv,
                                           q_raw, k_raw, v_raw);
    // 2) RoPE + scatter (+ new_key/new_value tails)
    rope_scatter<<<NTOK, 256, 0, stream>>>(q_raw, k_raw, v_raw, pos, Qh, nk, nv);
    // 3) fused KV copy + partial attention
    attn_partial<<<dim3(nchunks, 128), 256, 0, stream>>>(past_k, past_v, Qh, amask,
                                                         nk, nv, pc, pm, pl, nchunks);
    // 4) merge partials -> ctx (token, hid)
    attn_reduce<<<128, 256, 0, stream>>>(pc, pm, pl, ctxw, nchunks);
    // 5) output projection
    gemm3<<<dim3(16, 4), 256, 0, stream>>>(ctxw, Wo, Wo, Wo, bo, bo, bo,
                                           out, out, out);
}